// Round 14
// baseline (706.761 us; speedup 1.0000x reference)
//
#include <hip/hip_runtime.h>

#define N_ROWS 131072
#define DIM    128
#define QST    4
#define KC     1024
#define BM     128     // rows per workgroup (4 waves x 32 rows)
#define NTH    256
#define PNTH   256
#define NWAVE  4
#define NCHUNK 64      // 16 codes per chunk
#define EPS    6e-3f   // certified fp16-split argmin margin
#define FLAGB  (1 << 16)

typedef _Float16 h8  __attribute__((ext_vector_type(8)));
typedef float    fx4 __attribute__((ext_vector_type(4)));

#define MFMA16(a, b, c) __builtin_amdgcn_mfma_f32_16x16x32_f16((a), (b), (c), 0, 0, 0)

// packB halfs layout: [q][ch(64)][kt(4)][hl(2)][lane(64)][j(8)]
__global__ void k_prep(const float* __restrict__ cb,
                       double* __restrict__ cvec64, float* __restrict__ cvec32,
                       _Float16* __restrict__ packB) {
  int gid = blockIdx.x * blockDim.x + threadIdx.x;
  if (gid >= QST * KC) return;
  int q = gid >> 10, code = gid & (KC - 1);
  int ch = code >> 4, n = code & 15;
  const float* e = cb + ((size_t)q * KC + code) * DIM;
  double s = 0.0;
  for (int d = 0; d < DIM; d++) {
    float v = e[d];
    s = fma((double)v, (double)v, s);
    int kt = d >> 5, g = (d >> 3) & 3, j = d & 7;
    int lane = g * 16 + n;
    size_t base = ((size_t)q * NCHUNK + ch) * 4096 + (size_t)kt * 1024 + lane * 8 + j;
    _Float16 hh = (_Float16)v;
    packB[base]       = hh;                          // hi
    packB[base + 512] = (_Float16)(v - (float)hh);   // lo
  }
  cvec64[q * KC + code] = s;
  cvec32[q * KC + code] = (float)s;
}

__global__ __launch_bounds__(NTH, 2) void k_stage(
    int st, const float* rin, float* rout, const float* __restrict__ x,
    const float* __restrict__ cb,
    const double* __restrict__ cvec64, const float* __restrict__ cvec32,
    const _Float16* __restrict__ packB,
    float* __restrict__ oidx, float* __restrict__ lpart, int final_stage)
{
  __shared__ float  cvecL[KC];     // 4 KB
  __shared__ int    idxs[BM];
  __shared__ double redd[NWAVE];
  __shared__ int    redi[NWAVE];
  __shared__ float  redf[NWAVE];
  __shared__ int    flags[NWAVE];

  const int tid = threadIdx.x;
  const int lane = tid & 63, wv = tid >> 6;
  const int tx = lane & 15;
  const size_t rowbase = (size_t)blockIdx.x * BM;

  const double*   cq64 = cvec64 + st * KC;
  const float*    cq32 = cvec32 + st * KC;
  const float*    Eq   = cb + (size_t)st * KC * DIM;
  const _Float16* PBq  = packB + (size_t)st * 262144;

  for (int i = tid; i < KC; i += NTH) cvecL[i] = cq32[i];

  // ---- A-fragments: 2 rowtiles x 4 ktiles, fp16 hi/lo, straight from global
  h8 ah[2][4], al[2][4];
  #pragma unroll
  for (int rt = 0; rt < 2; rt++) {
    const float* rowp = rin + (rowbase + wv * 32 + rt * 16 + (lane & 15)) * (size_t)DIM
                        + ((lane >> 4) * 8);
    #pragma unroll
    for (int kt = 0; kt < 4; kt++) {
      float4 f0 = *(const float4*)(rowp + kt * 32);
      float4 f1 = *(const float4*)(rowp + kt * 32 + 4);
      float vv[8] = {f0.x, f0.y, f0.z, f0.w, f1.x, f1.y, f1.z, f1.w};
      #pragma unroll
      for (int j = 0; j < 8; j++) {
        _Float16 hh = (_Float16)vv[j];
        ah[rt][kt][j] = hh;
        al[rt][kt][j] = (_Float16)(vv[j] - (float)hh);
      }
    }
  }

  __syncthreads();   // cvecL visible (only block-wide sync before reduction)

  // ---- B streamed straight to VGPRs: no LDS, no DMA, no barriers in the loop
  h8 B0[8], B1[8];
  auto loadB = [&](int c, h8* B) {
    const _Float16* src = PBq + (size_t)c * 4096 + lane * 8;
    #pragma unroll
    for (int i = 0; i < 8; i++) B[i] = *(const h8*)(src + i * 512);
  };

  float b1v[8], b2v[8];
  int   i1v[8];
  #pragma unroll
  for (int i = 0; i < 8; i++) { b1v[i] = 3.4e38f; b2v[i] = 3.4e38f; i1v[i] = 0; }

  const fx4 zero4 = {0.f, 0.f, 0.f, 0.f};

  auto score = [&](int c, fx4* a) {
    int code = c * 16 + tx;
    float cvv = cvecL[code];
    #pragma unroll
    for (int rt = 0; rt < 2; rt++) {
      #pragma unroll
      for (int j = 0; j < 4; j++) {
        float sc = fmaf(-2.f, a[rt][j], cvv);
        int r = rt * 4 + j;
        if (sc < b1v[r]) { b2v[r] = b1v[r]; b1v[r] = sc; i1v[r] = code; }
        else             { b2v[r] = fminf(b2v[r], sc); }
      }
    }
  };

  auto mfmaC = [&](const h8* B, fx4* acc) {
    acc[0] = zero4; acc[1] = zero4;
    __builtin_amdgcn_s_setprio(1);
    #pragma unroll
    for (int kt = 0; kt < 4; kt++) {
      h8 bh = B[2 * kt];
      h8 bl = B[2 * kt + 1];
      #pragma unroll
      for (int rt = 0; rt < 2; rt++) {
        acc[rt] = MFMA16(ah[rt][kt], bh, acc[rt]);
        acc[rt] = MFMA16(al[rt][kt], bh, acc[rt]);
        acc[rt] = MFMA16(ah[rt][kt], bl, acc[rt]);
      }
    }
    __builtin_amdgcn_s_setprio(0);
  };

  loadB(0, B0); loadB(1, B1);
  fx4 accP[2] = {zero4, zero4};
  fx4 acc0[2], acc1[2];

  #pragma unroll 1
  for (int ch = 0; ch < NCHUNK; ch += 2) {
    if (ch > 0) score(ch - 1, accP);     // deferred: independent of MFMAs below
    mfmaC(B0, acc0);                     // chunk ch (reads B0)
    if (ch + 2 < NCHUNK) loadB(ch + 2, B0);
    score(ch, acc0);
    mfmaC(B1, acc1);                     // chunk ch+1 (reads B1)
    if (ch + 3 < NCHUNK) loadB(ch + 3, B1);
    accP[0] = acc1[0]; accP[1] = acc1[1];
  }
  score(NCHUNK - 1, accP);               // tail

  // ---- cross-lane top-2 reduce over the 16 lanes sharing each row
  #pragma unroll
  for (int m = 1; m < 16; m <<= 1) {
    #pragma unroll
    for (int r = 0; r < 8; r++) {
      float ob1 = __shfl_xor(b1v[r], m, 64);
      int   oi1 = __shfl_xor(i1v[r], m, 64);
      float ob2 = __shfl_xor(b2v[r], m, 64);
      bool take = (ob1 < b1v[r]) || (ob1 == b1v[r] && oi1 < i1v[r]);
      float loser = take ? b1v[r] : ob1;
      if (take) { b1v[r] = ob1; i1v[r] = oi1; }
      b2v[r] = fminf(fminf(b2v[r], ob2), loser);
    }
  }

  if (tx == 0) {
    int g = lane >> 4;
    #pragma unroll
    for (int rt = 0; rt < 2; rt++)
      #pragma unroll
      for (int j = 0; j < 4; j++) {
        int r = rt * 4 + j;
        int fl = (b2v[r] - b1v[r] <= EPS) ? FLAGB : 0;
        idxs[wv * 32 + rt * 16 + g * 4 + j] = i1v[r] | fl;
      }
  }
  __syncthreads();

  // ---- exact fp64 rescue for uncertain rows (rare); reads codebook rows
  {
    bool pred = (tid < BM) && (idxs[tid] & FLAGB);
    unsigned long long bal = __ballot(pred);
    if (lane == 0) flags[wv] = (bal != 0ull) ? 1 : 0;
  }
  __syncthreads();
  int anyflag = flags[0] | flags[1] | flags[2] | flags[3];
  if (anyflag) {
    for (int row = 0; row < BM; row++) {
      if (!(idxs[row] & FLAGB)) continue;          // uniform branch
      const float* rrow = rin + (rowbase + row) * (size_t)DIM;
      double dot[4] = {0.0, 0.0, 0.0, 0.0};
      for (int d = 0; d < DIM; d++) {
        double a = (double)rrow[d];                // broadcast load
        #pragma unroll
        for (int c = 0; c < 4; c++)
          dot[c] = fma(a, (double)Eq[(size_t)(tid + c * NTH) * DIM + d], dot[c]);
      }
      double bs = 1e300; int bk = 0;
      #pragma unroll
      for (int c = 0; c < 4; c++) {
        int k = tid + c * NTH;
        double s = fma(-2.0, dot[c], cq64[k]);
        if (s < bs || (s == bs && k < bk)) { bs = s; bk = k; }
      }
      #pragma unroll
      for (int m = 1; m < 64; m <<= 1) {
        double ob = __shfl_xor(bs, m, 64);
        int    ok = __shfl_xor(bk, m, 64);
        if (ob < bs || (ob == bs && ok < bk)) { bs = ob; bk = ok; }
      }
      if (lane == 0) { redd[wv] = bs; redi[wv] = bk; }
      __syncthreads();
      if (tid == 0) {
        double fb = redd[0]; int fk = redi[0];
        #pragma unroll
        for (int w = 1; w < NWAVE; w++) {
          if (redd[w] < fb || (redd[w] == fb && redi[w] < fk)) { fb = redd[w]; fk = redi[w]; }
        }
        idxs[row] = fk;                            // flag cleared
      }
      __syncthreads();
    }
  }

  // ---- fused epilogue, fully coalesced flat writes:
  //      r_new = r_old - E[idx]; loss += (E[idx]-r_old)^2; last stage: out = x - r_new
  {
    float lsum = 0.f;
    #pragma unroll 1
    for (int it = 0; it < 16; it++) {
      int g = it * NTH + tid;
      int row = g >> 5, c4 = g & 31;
      int kidx = idxs[row] & 1023;
      if ((g & 31) == 0) oidx[(rowbase + row) * 4 + st] = (float)kidx;
      float4 ev = *(const float4*)(Eq + (size_t)kidx * DIM + c4 * 4);
      float4 rv = *(const float4*)(rin + (rowbase + row) * (size_t)DIM + c4 * 4);
      float4 dv = make_float4(rv.x - ev.x, rv.y - ev.y, rv.z - ev.z, rv.w - ev.w);
      lsum = fmaf(dv.x, dv.x, lsum);
      lsum = fmaf(dv.y, dv.y, lsum);
      lsum = fmaf(dv.z, dv.z, lsum);
      lsum = fmaf(dv.w, dv.w, lsum);
      float4 wv4 = dv;
      if (final_stage) {
        float4 xv = *(const float4*)(x + (rowbase + row) * (size_t)DIM + c4 * 4);
        wv4 = make_float4(xv.x - dv.x, xv.y - dv.y, xv.z - dv.z, xv.w - dv.w);
      }
      *(float4*)(rout + (rowbase + row) * (size_t)DIM + c4 * 4) = wv4;
    }
    #pragma unroll
    for (int m = 1; m < 64; m <<= 1) lsum += __shfl_xor(lsum, m, 64);
    if (lane == 0) redf[wv] = lsum;
    __syncthreads();
    if (tid == 0) lpart[st * (N_ROWS / BM) + blockIdx.x] =
        redf[0] + redf[1] + redf[2] + redf[3];
  }
}

__global__ void k_loss(const float* __restrict__ part, float* __restrict__ o) {
  __shared__ float red[4];
  int tid = threadIdx.x;
  float s = 0.f;
  for (int i = tid; i < QST * (N_ROWS / BM); i += PNTH) s += part[i];
  #pragma unroll
  for (int m = 1; m < 64; m <<= 1) s += __shfl_xor(s, m, 64);
  if ((tid & 63) == 0) red[tid >> 6] = s;
  __syncthreads();
  if (tid == 0)
    o[0] = (red[0] + red[1] + red[2] + red[3]) *
           (1.25f / ((float)QST * (float)N_ROWS * (float)DIM));
}

extern "C" void kernel_launch(void* const* d_in, const int* in_sizes, int n_in,
                              void* d_out, int out_size, void* d_ws, size_t ws_size,
                              hipStream_t stream) {
  const float* x  = (const float*)d_in[0];
  const float* cb = (const float*)d_in[1];
  float* out = (float*)d_out;
  float* ws  = (float*)d_ws;

  float*    r      = out;                                   // residual in x_q region
  double*   cvec64 = (double*)ws;                           // Q*K fp64 ||E||^2
  float*    cvec32 = (float*)(cvec64 + (size_t)QST * KC);
  float*    part   = cvec32 + (size_t)QST * KC;             // Q*1024 partials
  _Float16* packB  = (_Float16*)(part + (size_t)QST * (N_ROWS / BM)); // 2 MB frags

  float* out_loss = out + (size_t)N_ROWS * DIM;
  float* out_idx  = out_loss + 1;

  k_prep<<<(QST * KC + PNTH - 1) / PNTH, PNTH, 0, stream>>>(cb, cvec64, cvec32, packB);

  for (int s = 0; s < QST; s++) {
    const float* rin = (s == 0) ? x : r;
    k_stage<<<N_ROWS / BM, NTH, 0, stream>>>(s, rin, r, x, cb, cvec64, cvec32,
                                             packB, out_idx, part,
                                             (s == QST - 1) ? 1 : 0);
  }

  k_loss<<<1, PNTH, 0, stream>>>(part, out_loss);
}

// Round 15
// 705.666 us; speedup vs baseline: 1.0016x; 1.0016x over previous
//
#include <hip/hip_runtime.h>

#define N_ROWS 131072
#define DIM    128
#define QST    4
#define KC     1024
#define BM     128     // rows per workgroup (4 waves x 32 rows)
#define NTH    256
#define PNTH   256
#define NWAVE  4
#define NCHUNK 64      // 16 codes per chunk
#define EPS    6e-3f   // certified fp16-split argmin margin
#define FLAGB  (1 << 16)

typedef _Float16 h8  __attribute__((ext_vector_type(8)));
typedef float    fx4 __attribute__((ext_vector_type(4)));

#define MFMA16(a, b, c) __builtin_amdgcn_mfma_f32_16x16x32_f16((a), (b), (c), 0, 0, 0)
#define SCHED_FENCE() __builtin_amdgcn_sched_barrier(0)

// packB halfs layout: [q][ch(64)][kt(4)][hl(2)][lane(64)][j(8)]
__global__ void k_prep(const float* __restrict__ cb,
                       double* __restrict__ cvec64, float* __restrict__ cvec32,
                       _Float16* __restrict__ packB) {
  int gid = blockIdx.x * blockDim.x + threadIdx.x;
  if (gid >= QST * KC) return;
  int q = gid >> 10, code = gid & (KC - 1);
  int ch = code >> 4, n = code & 15;
  const float* e = cb + ((size_t)q * KC + code) * DIM;
  double s = 0.0;
  for (int d = 0; d < DIM; d++) {
    float v = e[d];
    s = fma((double)v, (double)v, s);
    int kt = d >> 5, g = (d >> 3) & 3, j = d & 7;
    int lane = g * 16 + n;
    size_t base = ((size_t)q * NCHUNK + ch) * 4096 + (size_t)kt * 1024 + lane * 8 + j;
    _Float16 hh = (_Float16)v;
    packB[base]       = hh;                          // hi
    packB[base + 512] = (_Float16)(v - (float)hh);   // lo
  }
  cvec64[q * KC + code] = s;
  cvec32[q * KC + code] = (float)s;
}

__global__ __launch_bounds__(NTH, 2) void k_stage(
    int st, const float* rin, float* rout, const float* __restrict__ x,
    const float* __restrict__ cb,
    const double* __restrict__ cvec64, const float* __restrict__ cvec32,
    const _Float16* __restrict__ packB,
    float* __restrict__ oidx, float* __restrict__ lpart, int final_stage)
{
  __shared__ float  cvecL[KC];     // 4 KB
  __shared__ int    idxs[BM];
  __shared__ double redd[NWAVE];
  __shared__ int    redi[NWAVE];
  __shared__ float  redf[NWAVE];
  __shared__ int    flags[NWAVE];

  const int tid = threadIdx.x;
  const int lane = tid & 63, wv = tid >> 6;
  const int tx = lane & 15;
  const size_t rowbase = (size_t)blockIdx.x * BM;

  const double*   cq64 = cvec64 + st * KC;
  const float*    cq32 = cvec32 + st * KC;
  const float*    Eq   = cb + (size_t)st * KC * DIM;
  const _Float16* PBq  = packB + (size_t)st * 262144;

  for (int i = tid; i < KC; i += NTH) cvecL[i] = cq32[i];

  // ---- A-fragments: 2 rowtiles x 4 ktiles, fp16 hi/lo, straight from global
  h8 ah[2][4], al[2][4];
  #pragma unroll
  for (int rt = 0; rt < 2; rt++) {
    const float* rowp = rin + (rowbase + wv * 32 + rt * 16 + (lane & 15)) * (size_t)DIM
                        + ((lane >> 4) * 8);
    #pragma unroll
    for (int kt = 0; kt < 4; kt++) {
      float4 f0 = *(const float4*)(rowp + kt * 32);
      float4 f1 = *(const float4*)(rowp + kt * 32 + 4);
      float vv[8] = {f0.x, f0.y, f0.z, f0.w, f1.x, f1.y, f1.z, f1.w};
      #pragma unroll
      for (int j = 0; j < 8; j++) {
        _Float16 hh = (_Float16)vv[j];
        ah[rt][kt][j] = hh;
        al[rt][kt][j] = (_Float16)(vv[j] - (float)hh);
      }
    }
  }

  __syncthreads();   // cvecL visible (only block-wide sync before reduction)

  // ---- B streamed straight to VGPRs, register double-buffer B0/B1.
  //      sched_barrier(0) fences pin the load-issue points so the compiler
  //      cannot sink the prefetch into its use (round-14 failure: VGPR=96).
  h8 B0[8], B1[8];
  auto loadB = [&](int c, h8* B) {
    const _Float16* src = PBq + (size_t)c * 4096 + lane * 8;
    #pragma unroll
    for (int i = 0; i < 8; i++) B[i] = *(const h8*)(src + i * 512);
  };

  float b1v[8], b2v[8];
  int   i1v[8];
  #pragma unroll
  for (int i = 0; i < 8; i++) { b1v[i] = 3.4e38f; b2v[i] = 3.4e38f; i1v[i] = 0; }

  const fx4 zero4 = {0.f, 0.f, 0.f, 0.f};

  // score over summed accumulators (register-only)
  auto score = [&](int c, const fx4* a) {
    int code = c * 16 + tx;
    float cvv = cvecL[code];
    #pragma unroll
    for (int rt = 0; rt < 2; rt++) {
      #pragma unroll
      for (int j = 0; j < 4; j++) {
        float sc = fmaf(-2.f, a[rt][j], cvv);
        int r = rt * 4 + j;
        if (sc < b1v[r]) { b2v[r] = b1v[r]; b1v[r] = sc; i1v[r] = code; }
        else             { b2v[r] = fminf(b2v[r], sc); }
      }
    }
  };

  // 4 independent MFMA chains (depths 8,8,4,4) instead of 2x depth-12
  auto mfmaC = [&](const h8* B, fx4* accH, fx4* accL) {
    accH[0] = zero4; accH[1] = zero4; accL[0] = zero4; accL[1] = zero4;
    __builtin_amdgcn_s_setprio(1);
    #pragma unroll
    for (int kt = 0; kt < 4; kt++) {
      h8 bh = B[2 * kt];
      h8 bl = B[2 * kt + 1];
      #pragma unroll
      for (int rt = 0; rt < 2; rt++) {
        accH[rt] = MFMA16(ah[rt][kt], bh, accH[rt]);
        accH[rt] = MFMA16(al[rt][kt], bh, accH[rt]);
        accL[rt] = MFMA16(ah[rt][kt], bl, accL[rt]);
      }
    }
    __builtin_amdgcn_s_setprio(0);
  };

  loadB(0, B0); loadB(1, B1);
  SCHED_FENCE();
  fx4 accP[2] = {zero4, zero4};
  fx4 aH0[2], aL0[2], aH1[2], aL1[2], sum0[2];

  #pragma unroll 1
  for (int ch = 0; ch < NCHUNK; ch += 2) {
    // --- chunk ch: consume B0, immediately re-issue B0 loads for ch+2
    mfmaC(B0, aH0, aL0);
    if (ch + 2 < NCHUNK) loadB(ch + 2, B0);
    SCHED_FENCE();   // loads for ch+2 pinned here; waited at next iter's mfmaC(B0)

    // latency window for B0 refill: deferred + current scores, then mfmaC(B1)
    if (ch > 0) score(ch - 1, accP);
    sum0[0] = aH0[0] + aL0[0]; sum0[1] = aH0[1] + aL0[1];
    score(ch, sum0);

    // --- chunk ch+1: consume B1, re-issue B1 loads for ch+3
    mfmaC(B1, aH1, aL1);
    if (ch + 3 < NCHUNK) loadB(ch + 3, B1);
    SCHED_FENCE();   // loads for ch+3 pinned; waited at next iter's mfmaC(B1)

    accP[0] = aH1[0] + aL1[0]; accP[1] = aH1[1] + aL1[1];  // deferred to next iter
  }
  score(NCHUNK - 1, accP);               // tail

  // ---- cross-lane top-2 reduce over the 16 lanes sharing each row
  #pragma unroll
  for (int m = 1; m < 16; m <<= 1) {
    #pragma unroll
    for (int r = 0; r < 8; r++) {
      float ob1 = __shfl_xor(b1v[r], m, 64);
      int   oi1 = __shfl_xor(i1v[r], m, 64);
      float ob2 = __shfl_xor(b2v[r], m, 64);
      bool take = (ob1 < b1v[r]) || (ob1 == b1v[r] && oi1 < i1v[r]);
      float loser = take ? b1v[r] : ob1;
      if (take) { b1v[r] = ob1; i1v[r] = oi1; }
      b2v[r] = fminf(fminf(b2v[r], ob2), loser);
    }
  }

  if (tx == 0) {
    int g = lane >> 4;
    #pragma unroll
    for (int rt = 0; rt < 2; rt++)
      #pragma unroll
      for (int j = 0; j < 4; j++) {
        int r = rt * 4 + j;
        int fl = (b2v[r] - b1v[r] <= EPS) ? FLAGB : 0;
        idxs[wv * 32 + rt * 16 + g * 4 + j] = i1v[r] | fl;
      }
  }
  __syncthreads();

  // ---- exact fp64 rescue for uncertain rows (rare); reads codebook rows
  {
    bool pred = (tid < BM) && (idxs[tid] & FLAGB);
    unsigned long long bal = __ballot(pred);
    if (lane == 0) flags[wv] = (bal != 0ull) ? 1 : 0;
  }
  __syncthreads();
  int anyflag = flags[0] | flags[1] | flags[2] | flags[3];
  if (anyflag) {
    for (int row = 0; row < BM; row++) {
      if (!(idxs[row] & FLAGB)) continue;          // uniform branch
      const float* rrow = rin + (rowbase + row) * (size_t)DIM;
      double dot[4] = {0.0, 0.0, 0.0, 0.0};
      for (int d = 0; d < DIM; d++) {
        double a = (double)rrow[d];                // broadcast load
        #pragma unroll
        for (int c = 0; c < 4; c++)
          dot[c] = fma(a, (double)Eq[(size_t)(tid + c * NTH) * DIM + d], dot[c]);
      }
      double bs = 1e300; int bk = 0;
      #pragma unroll
      for (int c = 0; c < 4; c++) {
        int k = tid + c * NTH;
        double s = fma(-2.0, dot[c], cq64[k]);
        if (s < bs || (s == bs && k < bk)) { bs = s; bk = k; }
      }
      #pragma unroll
      for (int m = 1; m < 64; m <<= 1) {
        double ob = __shfl_xor(bs, m, 64);
        int    ok = __shfl_xor(bk, m, 64);
        if (ob < bs || (ob == bs && ok < bk)) { bs = ob; bk = ok; }
      }
      if (lane == 0) { redd[wv] = bs; redi[wv] = bk; }
      __syncthreads();
      if (tid == 0) {
        double fb = redd[0]; int fk = redi[0];
        #pragma unroll
        for (int w = 1; w < NWAVE; w++) {
          if (redd[w] < fb || (redd[w] == fb && redi[w] < fk)) { fb = redd[w]; fk = redi[w]; }
        }
        idxs[row] = fk;                            // flag cleared
      }
      __syncthreads();
    }
  }

  // ---- fused epilogue, fully coalesced flat writes:
  //      r_new = r_old - E[idx]; loss += (E[idx]-r_old)^2; last stage: out = x - r_new
  {
    float lsum = 0.f;
    #pragma unroll 1
    for (int it = 0; it < 16; it++) {
      int g = it * NTH + tid;
      int row = g >> 5, c4 = g & 31;
      int kidx = idxs[row] & 1023;
      if ((g & 31) == 0) oidx[(rowbase + row) * 4 + st] = (float)kidx;
      float4 ev = *(const float4*)(Eq + (size_t)kidx * DIM + c4 * 4);
      float4 rv = *(const float4*)(rin + (rowbase + row) * (size_t)DIM + c4 * 4);
      float4 dv = make_float4(rv.x - ev.x, rv.y - ev.y, rv.z - ev.z, rv.w - ev.w);
      lsum = fmaf(dv.x, dv.x, lsum);
      lsum = fmaf(dv.y, dv.y, lsum);
      lsum = fmaf(dv.z, dv.z, lsum);
      lsum = fmaf(dv.w, dv.w, lsum);
      float4 wv4 = dv;
      if (final_stage) {
        float4 xv = *(const float4*)(x + (rowbase + row) * (size_t)DIM + c4 * 4);
        wv4 = make_float4(xv.x - dv.x, xv.y - dv.y, xv.z - dv.z, xv.w - dv.w);
      }
      *(float4*)(rout + (rowbase + row) * (size_t)DIM + c4 * 4) = wv4;
    }
    #pragma unroll
    for (int m = 1; m < 64; m <<= 1) lsum += __shfl_xor(lsum, m, 64);
    if (lane == 0) redf[wv] = lsum;
    __syncthreads();
    if (tid == 0) lpart[st * (N_ROWS / BM) + blockIdx.x] =
        redf[0] + redf[1] + redf[2] + redf[3];
  }
}

__global__ void k_loss(const float* __restrict__ part, float* __restrict__ o) {
  __shared__ float red[4];
  int tid = threadIdx.x;
  float s = 0.f;
  for (int i = tid; i < QST * (N_ROWS / BM); i += PNTH) s += part[i];
  #pragma unroll
  for (int m = 1; m < 64; m <<= 1) s += __shfl_xor(s, m, 64);
  if ((tid & 63) == 0) red[tid >> 6] = s;
  __syncthreads();
  if (tid == 0)
    o[0] = (red[0] + red[1] + red[2] + red[3]) *
           (1.25f / ((float)QST * (float)N_ROWS * (float)DIM));
}

extern "C" void kernel_launch(void* const* d_in, const int* in_sizes, int n_in,
                              void* d_out, int out_size, void* d_ws, size_t ws_size,
                              hipStream_t stream) {
  const float* x  = (const float*)d_in[0];
  const float* cb = (const float*)d_in[1];
  float* out = (float*)d_out;
  float* ws  = (float*)d_ws;

  float*    r      = out;                                   // residual in x_q region
  double*   cvec64 = (double*)ws;                           // Q*K fp64 ||E||^2
  float*    cvec32 = (float*)(cvec64 + (size_t)QST * KC);
  float*    part   = cvec32 + (size_t)QST * KC;             // Q*1024 partials
  _Float16* packB  = (_Float16*)(part + (size_t)QST * (N_ROWS / BM)); // 2 MB frags

  float* out_loss = out + (size_t)N_ROWS * DIM;
  float* out_idx  = out_loss + 1;

  k_prep<<<(QST * KC + PNTH - 1) / PNTH, PNTH, 0, stream>>>(cb, cvec64, cvec32, packB);

  for (int s = 0; s < QST; s++) {
    const float* rin = (s == 0) ? x : r;
    k_stage<<<N_ROWS / BM, NTH, 0, stream>>>(s, rin, r, x, cb, cvec64, cvec32,
                                             packB, out_idx, part,
                                             (s == QST - 1) ? 1 : 0);
  }

  k_loss<<<1, PNTH, 0, stream>>>(part, out_loss);
}